// Round 12
// baseline (285.416 us; speedup 1.0000x reference)
//
#include <hip/hip_runtime.h>
#include <math.h>

#define NN 100000
#define NE 600000
#define DD 128
#define NTILES 6250          // NN / 16
#define NB_EDGES 2344        // ceil(NE/256)
#define NB_NODES 391         // ceil(NN/256)
#define NB_WT 128            // DD*256/256

typedef __attribute__((ext_vector_type(8))) __bf16 bf16x8;
typedef __attribute__((ext_vector_type(4))) float f32x4;

__device__ inline unsigned short f2bf(float f) {
    unsigned int u = __float_as_uint(f);
    unsigned int r = (u + 0x7fffu + ((u >> 16) & 1u)) >> 16;
    return (unsigned short)r;
}

// ---------------- hist of dst + stage combined weights (fused, independent work) ----------------
__global__ __launch_bounds__(256) void hist_wt_kernel(
    const int* __restrict__ ei, int* __restrict__ counts,
    const float* __restrict__ Wl2, const float* __restrict__ Wr2,
    unsigned short* __restrict__ WT)
{
    const int b = blockIdx.x;
    if (b < NB_EDGES) {
        int e = b * 256 + threadIdx.x;
        if (e < NE) atomicAdd(&counts[ei[NE + e]], 1);
    } else {
        int t = (b - NB_EDGES) * 256 + threadIdx.x;   // 0..32767 exact
        int n = t >> 8;
        int k = t & 255;
        float v = (k < DD) ? Wl2[n * DD + k] : Wr2[n * DD + (k - DD)];
        WT[t] = f2bf(v);
    }
}

// ---------------- scan level 1: per-block exclusive scan + raw block totals ----------------
__global__ __launch_bounds__(256) void scan1_kernel(const int* __restrict__ counts,
                                                    int* __restrict__ offsets,
                                                    int* __restrict__ partials, int n) {
    __shared__ int tmp[256];
    int i = blockIdx.x * 256 + threadIdx.x;
    int v = (i < n) ? counts[i] : 0;
    tmp[threadIdx.x] = v;
    __syncthreads();
    for (int off = 1; off < 256; off <<= 1) {
        int t = (threadIdx.x >= off) ? tmp[threadIdx.x - off] : 0;
        __syncthreads();
        tmp[threadIdx.x] += t;
        __syncthreads();
    }
    if (i < n) offsets[i] = tmp[threadIdx.x] - v;   // exclusive within block
    if (threadIdx.x == 255) partials[blockIdx.x] = tmp[255];   // raw block total
}

// ---------------- scan level 2+3 fused: each block derives its own prefix ----------------
__global__ __launch_bounds__(256) void scan23_kernel(int* __restrict__ offsets,
                                                     int* __restrict__ cursor,
                                                     const int* __restrict__ partials) {
    __shared__ int sbase;
    if (threadIdx.x == 0) sbase = 0;
    __syncthreads();
    int acc = 0;
    for (int i = threadIdx.x; i < blockIdx.x; i += 256) acc += partials[i];
    for (int off = 32; off > 0; off >>= 1) acc += __shfl_down(acc, off);
    if ((threadIdx.x & 63) == 0 && acc != 0) atomicAdd(&sbase, acc);
    __syncthreads();
    int i = blockIdx.x * 256 + threadIdx.x;
    if (i < NN) {
        int o = offsets[i] + sbase;
        offsets[i] = o;
        cursor[i]  = o;
    }
    if (i == 0) offsets[NN] = NE;
}

// ---------------- reorder: sorted_src ----------------
__global__ void reorder_kernel(const int* __restrict__ ei, int* __restrict__ cursor,
                               int* __restrict__ ssrc) {
    int e = blockIdx.x * blockDim.x + threadIdx.x;
    if (e < NE) {
        int pos = atomicAdd(&cursor[ei[NE + e]], 1);
        ssrc[pos] = ei[e];
    }
}

// ---------------- FUSED gather + MFMA GEMM + bias + L2 normalize ----------------
// Block = 256 threads, one 16-row tile. Phase 1: 8 half-waves gather 2 nodes
// each (mean+h, bf16) into swizzled LDS. Phase 2: 4 waves, B-resident MFMA,
// fused bias + row-L2-normalize, write out. A never touches global memory.
__global__ __launch_bounds__(256) void fused_agg_gemm_kernel(
    const float* __restrict__ x, const int* __restrict__ offsets,
    const int* __restrict__ ssrc,
    const float* __restrict__ bn_gamma, const float* __restrict__ bn_beta,
    const float* __restrict__ bn_mean, const float* __restrict__ bn_var,
    const unsigned short* __restrict__ WT, const float* __restrict__ bl,
    float* __restrict__ out)
{
    __shared__ unsigned short ldsA[16 * 256];   // 8 KB, XOR-swizzled rows
    __shared__ float partial[4][16];

    const int tid  = threadIdx.x;
    const int row0 = blockIdx.x * 16;

    // wave-view indices (phase 2)
    const int wave = tid >> 6;
    const int l    = tid & 63;
    const int r    = l & 15;        // A row in tile / B col in tile
    const int seg  = l >> 4;        // k-segment
    const int c0   = wave * 32;

    // ---- persistent B fragments: issued first, consumed after barrier ----
    bf16x8 bf0[8], bf1[8];
    {
        const unsigned short* bp0 = WT + (size_t)(c0 + r) * 256 + seg * 8;
        const unsigned short* bp1 = WT + (size_t)(c0 + 16 + r) * 256 + seg * 8;
#pragma unroll
        for (int kk = 0; kk < 8; ++kk) {
            bf0[kk] = *(const bf16x8*)(bp0 + kk * 32);
            bf1[kk] = *(const bf16x8*)(bp1 + kk * 32);
        }
    }
    const float bias0 = bl[c0 + r];
    const float bias1 = bl[c0 + 16 + r];

    // ---- phase 1: gather (half-wave per node, float4/lane) ----
    {
        const int g  = tid >> 5;          // group 0..7
        const int gl = tid & 31;
        const int c  = gl * 4;            // feature base

        const float4 bm = *(const float4*)(bn_mean  + c);
        const float4 bv = *(const float4*)(bn_var   + c);
        const float4 bg = *(const float4*)(bn_gamma + c);
        const float4 bb = *(const float4*)(bn_beta  + c);
        const float sc0 = rsqrtf(bv.x + 1e-5f) * bg.x;
        const float sc1 = rsqrtf(bv.y + 1e-5f) * bg.y;
        const float sc2 = rsqrtf(bv.z + 1e-5f) * bg.z;
        const float sc3 = rsqrtf(bv.w + 1e-5f) * bg.w;
        const float* xb = x + c;

#pragma unroll 1
        for (int it = 0; it < 2; ++it) {
            const int nt   = g * 2 + it;      // row in tile 0..15
            const int node = row0 + nt;

            const int st = offsets[node], en = offsets[node + 1];
            float s0 = 0.f, s1 = 0.f, s2 = 0.f, s3 = 0.f;
            int j = st;
            for (; j + 4 <= en; j += 4) {
                const int4 ss = *(const int4*)(ssrc + j);
                float4 v0 = *(const float4*)(xb + (size_t)ss.x * DD);
                float4 v1 = *(const float4*)(xb + (size_t)ss.y * DD);
                float4 v2 = *(const float4*)(xb + (size_t)ss.z * DD);
                float4 v3 = *(const float4*)(xb + (size_t)ss.w * DD);
                s0 += fmaxf(v0.x, 0.f) + fmaxf(v1.x, 0.f) + fmaxf(v2.x, 0.f) + fmaxf(v3.x, 0.f);
                s1 += fmaxf(v0.y, 0.f) + fmaxf(v1.y, 0.f) + fmaxf(v2.y, 0.f) + fmaxf(v3.y, 0.f);
                s2 += fmaxf(v0.z, 0.f) + fmaxf(v1.z, 0.f) + fmaxf(v2.z, 0.f) + fmaxf(v3.z, 0.f);
                s3 += fmaxf(v0.w, 0.f) + fmaxf(v1.w, 0.f) + fmaxf(v2.w, 0.f) + fmaxf(v3.w, 0.f);
            }
            for (; j < en; ++j) {
                int s = ssrc[j];
                float4 v = *(const float4*)(xb + (size_t)s * DD);
                s0 += fmaxf(v.x, 0.f);
                s1 += fmaxf(v.y, 0.f);
                s2 += fmaxf(v.z, 0.f);
                s3 += fmaxf(v.w, 0.f);
            }

            const int deg = en - st;
            float m0, m1, m2, m3;
            if (deg > 0) {
                float inv = 1.0f / (float)deg;
                m0 = (s0 * inv - bm.x) * sc0 + bb.x;   // BN affine commutes with mean
                m1 = (s1 * inv - bm.y) * sc1 + bb.y;
                m2 = (s2 * inv - bm.z) * sc2 + bb.z;
                m3 = (s3 * inv - bm.w) * sc3 + bb.w;
            } else {
                m0 = m1 = m2 = m3 = 0.f;
            }

            const float4 xv = *(const float4*)(xb + (size_t)node * DD);
            float h0 = (fmaxf(xv.x, 0.f) - bm.x) * sc0 + bb.x;
            float h1 = (fmaxf(xv.y, 0.f) - bm.y) * sc1 + bb.y;
            float h2 = (fmaxf(xv.z, 0.f) - bm.z) * sc2 + bb.z;
            float h3 = (fmaxf(xv.w, 0.f) - bm.w) * sc3 + bb.w;

            ushort4 mm; mm.x = f2bf(m0); mm.y = f2bf(m1); mm.z = f2bf(m2); mm.w = f2bf(m3);
            ushort4 hh; hh.x = f2bf(h0); hh.y = f2bf(h1); hh.z = f2bf(h2); hh.w = f2bf(h3);

            // swizzled LDS write: byte_in_row ^= (row&7)<<4  (keeps 8B alignment)
            const int swz = (nt & 7) << 4;
            char* rowp = (char*)ldsA + nt * 512;
            *(ushort4*)(rowp + ((c * 2) ^ swz))       = mm;
            *(ushort4*)(rowp + ((256 + c * 2) ^ swz)) = hh;
        }
    }
    __syncthreads();

    // ---- phase 2: MFMA from swizzled LDS ----
    bf16x8 af[8];
#pragma unroll
    for (int kk = 0; kk < 8; ++kk) {
        const int o = (seg * 16 + kk * 64) ^ ((r & 7) << 4);
        af[kk] = *(const bf16x8*)((const char*)ldsA + r * 512 + o);
    }

    f32x4 acc0 = {0.f, 0.f, 0.f, 0.f};
    f32x4 acc1 = {0.f, 0.f, 0.f, 0.f};
#pragma unroll
    for (int kk = 0; kk < 8; ++kk) {
        acc0 = __builtin_amdgcn_mfma_f32_16x16x32_bf16(af[kk], bf0[kk], acc0, 0, 0, 0);
        acc1 = __builtin_amdgcn_mfma_f32_16x16x32_bf16(af[kk], bf1[kk], acc1, 0, 0, 0);
    }

    // C/D layout: col = lane&15, row = (lane>>4)*4 + q  [m89-verified]
    float p[4];
#pragma unroll
    for (int q = 0; q < 4; ++q) {
        acc0[q] += bias0;
        acc1[q] += bias1;
        p[q] = acc0[q] * acc0[q] + acc1[q] * acc1[q];
    }
#pragma unroll
    for (int m = 1; m < 16; m <<= 1) {
#pragma unroll
        for (int q = 0; q < 4; ++q) p[q] += __shfl_xor(p[q], m);
    }
    if (r == 0) {
#pragma unroll
        for (int q = 0; q < 4; ++q) partial[wave][seg * 4 + q] = p[q];
    }
    __syncthreads();

#pragma unroll
    for (int q = 0; q < 4; ++q) {
        const int rr = seg * 4 + q;
        float s = partial[0][rr] + partial[1][rr] + partial[2][rr] + partial[3][rr];
        float inv = 1.0f / fmaxf(sqrtf(s), 1e-12f);
        float* orow = out + (size_t)(row0 + rr) * DD;
        orow[c0 + r]      = acc0[q] * inv;
        orow[c0 + 16 + r] = acc1[q] * inv;
    }
}

extern "C" void kernel_launch(void* const* d_in, const int* in_sizes, int n_in,
                              void* d_out, int out_size, void* d_ws, size_t ws_size,
                              hipStream_t stream) {
    const float* x        = (const float*)d_in[0];
    const int*   ei       = (const int*)d_in[1];
    const float* Wl2      = (const float*)d_in[5];
    const float* bl2      = (const float*)d_in[6];
    const float* Wr2      = (const float*)d_in[7];
    const float* bn_gamma = (const float*)d_in[8];
    const float* bn_beta  = (const float*)d_in[9];
    const float* bn_mean  = (const float*)d_in[10];
    const float* bn_var   = (const float*)d_in[11];
    float* out = (float*)d_out;

    // workspace layout (A eliminated)
    unsigned short* WT = (unsigned short*)d_ws;             // DD*256 bf16 (64 KB)
    int* counts   = (int*)(WT + DD * 256);                  // NN
    int* offsets  = counts + NN;                            // NN+1
    int* cursor   = offsets + NN + 1;                       // NN
    int* partials = cursor + NN;                            // 512
    int* ssrc     = partials + 512;                         // NE

    hipMemsetAsync(counts, 0, NN * sizeof(int), stream);
    hist_wt_kernel<<<NB_EDGES + NB_WT, 256, 0, stream>>>(ei, counts, Wl2, Wr2, WT);
    scan1_kernel<<<NB_NODES, 256, 0, stream>>>(counts, offsets, partials, NN);
    scan23_kernel<<<NB_NODES, 256, 0, stream>>>(offsets, cursor, partials);
    reorder_kernel<<<NB_EDGES, 256, 0, stream>>>(ei, cursor, ssrc);
    fused_agg_gemm_kernel<<<NTILES, 256, 0, stream>>>(
        x, offsets, ssrc, bn_gamma, bn_beta, bn_mean, bn_var, WT, bl2, out);
}